// Round 5
// baseline (1603.483 us; speedup 1.0000x reference)
//
#include <hip/hip_runtime.h>

// QGrouping fused pipeline v3 (resubmit r5; r4 never ran - GPU timeout).
//   weights = x @ (Wq@Wk)^T + (Wq@bk+bq)   -- key[N,100] never materialized
//   e = exp(weights)  (no max-subtract: |w|<~3, f32-safe; softmax shift-invariant)
//   k_main fuses: GEMV (40 outs) + exp + segment outer-product reduce.
//   val[N,32] never touches HBM.  k_final normalizes embs and norm_w.
// r3 profile: k_main 433us, VALUBusy 21.5%, hbm 8% -> latency-bound on the
// per-chunk vmcnt(0)+barrier stall (no dbuf). This version: T14 issue-early/
// write-late reg-staged double buffer, 1 barrier/chunk, compute covers latency.

#define NSEG 128
#define KQ 8
#define VD 32
#define NOUT 40    // KQ + VD
#define INDIM 256
#define ROWS 256   // rows per block == block size
#define CCH 16     // x columns per chunk
#define NCH (INDIM / CCH)   // 16 chunks
#define XSTR 20    // CCH+4 dwords: 20*l mod 32 distinct for l=0..7 -> conflict-free b128
#define ESTR 12    // KQ+4  (b128-aligned, conflict-free write groups)
#define VSTR 36    // VD+4
#define SMEMF (ROWS * (ESTR + VSTR))   // 12288 floats = 48KB >= 2*ROWS*XSTR (40KB)

// ---------------- setup: combined weights + zero embs/segsum ----------------
__global__ __launch_bounds__(256) void k_setup(
    const float* __restrict__ Wk, const float* __restrict__ bk,
    const float* __restrict__ Wq, const float* __restrict__ bq,
    const float* __restrict__ Wv, const float* __restrict__ bv,
    float* __restrict__ WO, float* __restrict__ bo,
    float* __restrict__ segsum, float* __restrict__ embs) {
    int b = blockIdx.x;
    int c = threadIdx.x;
    if (b < NOUT) {
        if (b < KQ) {
            float a = 0.f;
            for (int j = 0; j < 100; ++j) a = fmaf(Wq[b * 100 + j], Wk[j * INDIM + c], a);
            WO[b * INDIM + c] = a;
            if (c == 0) {
                float s = bq[b];
                for (int j = 0; j < 100; ++j) s = fmaf(Wq[b * 100 + j], bk[j], s);
                bo[b] = s;
            }
        } else {
            int v = b - KQ;
            WO[b * INDIM + c] = Wv[v * INDIM + c];
            if (c == 0) bo[b] = bv[v];
        }
    } else {
        int i = (b - NOUT) * 256 + c;
        if (i < NSEG * KQ * VD) {
            embs[i] = 0.f;
        } else {
            int j = i - NSEG * KQ * VD;
            if (j < NSEG * KQ) segsum[j] = 0.f;
        }
    }
}

// ---------------- main: dbuf GEMV + exp + fused seg-reduction ----------------
__global__ __launch_bounds__(ROWS, 3) void k_main(
    const float* __restrict__ x, const int* __restrict__ batch,
    const float* __restrict__ WO, const float* __restrict__ bo,
    float* __restrict__ eout,          // d_out norm_w region: holds e for now
    float* __restrict__ segsum, float* __restrict__ embs, int N) {
    __shared__ float smem[SMEMF];      // union: {xsA|xsB dbuf} then {es|vs}
    __shared__ int sg[ROWS];
    const int tid = threadIdx.x;
    const int row0 = blockIdx.x * ROWS;
    const int row = row0 + tid;
    const bool valid = row < N;

    sg[tid] = valid ? batch[row] : batch[N - 1];

    float acc[NOUT];
#pragma unroll
    for (int o = 0; o < NOUT; ++o) acc[o] = bo[o];   // uniform -> s_load

    float* xsA = smem;                 // compute buffer
    float* xsB = smem + ROWS * XSTR;   // staging buffer
    const int srl = tid >> 2;          // staging: 4 threads per row-slice
    const int sc = (tid & 3) << 2;     // 16B sub-offset

    // prologue: stage chunk 0
    {
        float4 st[4];
#pragma unroll
        for (int i = 0; i < 4; ++i) {
            int rr = row0 + i * 64 + srl;
            st[i] = (rr < N) ? *(const float4*)&x[(size_t)rr * INDIM + sc]
                             : make_float4(0.f, 0.f, 0.f, 0.f);
        }
#pragma unroll
        for (int i = 0; i < 4; ++i)
            *(float4*)&xsA[(i * 64 + srl) * XSTR + sc] = st[i];
    }
    __syncthreads();

    for (int ch = 0; ch < NCH; ++ch) {
        float4 st[4];
        const bool more = (ch + 1 < NCH);
        if (more) {   // issue-early: next chunk's loads in flight during compute
            const int ccn = (ch + 1) * CCH;
#pragma unroll
            for (int i = 0; i < 4; ++i) {
                int rr = row0 + i * 64 + srl;
                st[i] = (rr < N) ? *(const float4*)&x[(size_t)rr * INDIM + ccn + sc]
                                 : make_float4(0.f, 0.f, 0.f, 0.f);
            }
        }
        const int cc = ch * CCH;
#pragma unroll
        for (int c4 = 0; c4 < CCH; c4 += 4) {
            float4 xv = *(const float4*)&xsA[tid * XSTR + c4];
            const float* wp = &WO[cc + c4];
#pragma unroll
            for (int o = 0; o < NOUT; ++o) {
                const float* w = wp + o * INDIM;   // uniform -> scalar loads
                acc[o] = fmaf(xv.x, w[0],
                         fmaf(xv.y, w[1],
                         fmaf(xv.z, w[2],
                         fmaf(xv.w, w[3], acc[o]))));
            }
        }
        if (more) {   // write-late (compiler inserts the vmcnt wait on st use)
#pragma unroll
            for (int i = 0; i < 4; ++i)
                *(float4*)&xsB[(i * 64 + srl) * XSTR + sc] = st[i];
        }
        __syncthreads();   // staged writes visible; old buffer free for reuse
        float* t = xsA; xsA = xsB; xsB = t;
    }
    // barrier above also fences last compute before smem is repurposed

    float e[KQ];
#pragma unroll
    for (int k = 0; k < KQ; ++k) e[k] = valid ? expf(acc[k]) : 0.f;

    if (valid) {   // stash unnormalized e; k_final normalizes in place
        *(float4*)&eout[(size_t)row * KQ]     = make_float4(e[0], e[1], e[2], e[3]);
        *(float4*)&eout[(size_t)row * KQ + 4] = make_float4(e[4], e[5], e[6], e[7]);
    }

    float* es = smem;                  // [ROWS][ESTR]
    float* vs = smem + ROWS * ESTR;    // [ROWS][VSTR]
    *(float4*)&es[tid * ESTR]     = make_float4(e[0], e[1], e[2], e[3]);
    *(float4*)&es[tid * ESTR + 4] = make_float4(e[4], e[5], e[6], e[7]);
#pragma unroll
    for (int i = 0; i < VD; i += 4)
        *(float4*)&vs[tid * VSTR + i] = make_float4(acc[KQ + i], acc[KQ + i + 1],
                                                    acc[KQ + i + 2], acc[KQ + i + 3]);
    __syncthreads();

    // thread owns one (k,vcol); serial over the block's 256 sorted rows.
    // es read: 2-address broadcast/wave. vs read: bank-distinct + bcast pair.
    const int kk = tid >> 5;       // 0..7
    const int vcol = tid & 31;
    float a0 = 0.f, s0 = 0.f;
    int cur = sg[0];
    for (int r = 0; r < ROWS; ++r) {
        int s = sg[r];                       // block-uniform (sorted segments)
        if (s != cur) {                      // rare (~1-2 flushes per block)
            atomicAdd(&embs[cur * (KQ * VD) + tid], a0);
            if (vcol == 0) atomicAdd(&segsum[cur * KQ + kk], s0);
            a0 = 0.f; s0 = 0.f; cur = s;
        }
        float ev = es[r * ESTR + kk];
        float vv = vs[r * VSTR + vcol];
        a0 = fmaf(ev, vv, a0);
        s0 += ev;
    }
    atomicAdd(&embs[cur * (KQ * VD) + tid], a0);
    if (vcol == 0) atomicAdd(&segsum[cur * KQ + kk], s0);
}

// ---------------- final: normalize embs and norm_w ----------------
__global__ __launch_bounds__(256) void k_final(
    float* __restrict__ wnorm, const int* __restrict__ batch,
    const float* __restrict__ segsum, float* __restrict__ embs, int N) {
    int gid = blockIdx.x * 256 + threadIdx.x;
    if (gid < NSEG * KQ * VD) {
        embs[gid] = embs[gid] / segsum[gid >> 5];   // (b*8+k) = gid>>5
    }
    if (gid < N) {
        int s = batch[gid];
        float4 e0 = *(float4*)&wnorm[(size_t)gid * KQ];
        float4 e1 = *(float4*)&wnorm[(size_t)gid * KQ + 4];
        const float* ss = &segsum[s * KQ];
        e0.x /= ss[0]; e0.y /= ss[1]; e0.z /= ss[2]; e0.w /= ss[3];
        e1.x /= ss[4]; e1.y /= ss[5]; e1.z /= ss[6]; e1.w /= ss[7];
        *(float4*)&wnorm[(size_t)gid * KQ]     = e0;
        *(float4*)&wnorm[(size_t)gid * KQ + 4] = e1;
    }
}

extern "C" void kernel_launch(void* const* d_in, const int* in_sizes, int n_in,
                              void* d_out, int out_size, void* d_ws, size_t ws_size,
                              hipStream_t stream) {
    const float* x   = (const float*)d_in[0];
    const int* batch = (const int*)d_in[1];
    const float* Wk  = (const float*)d_in[2];
    const float* bk  = (const float*)d_in[3];
    const float* Wq  = (const float*)d_in[4];
    const float* bq  = (const float*)d_in[5];
    const float* Wv  = (const float*)d_in[6];
    const float* bv  = (const float*)d_in[7];
    const int N = in_sizes[1];

    float* ws_f = (float*)d_ws;
    float* WO = ws_f;                                  // 40*256 floats
    float* bo = ws_f + NOUT * INDIM;                   // 40
    float* segsum = ws_f + NOUT * INDIM + NOUT + 8;    // 1024 floats, 16B-aligned

    float* embs  = (float*)d_out;                      // [128*8*32]
    float* wnorm = (float*)d_out + NSEG * KQ * VD;     // [N*8]: e -> norm_w in place

    {
        int nb = NOUT + (NSEG * KQ * VD + NSEG * KQ + 255) / 256;   // 40 + 132
        k_setup<<<nb, 256, 0, stream>>>(Wk, bk, Wq, bq, Wv, bv, WO, bo, segsum, embs);
    }
    {
        int nb = (N + ROWS - 1) / ROWS;
        k_main<<<nb, ROWS, 0, stream>>>(x, batch, WO, bo, wnorm, segsum, embs, N);
    }
    {
        int nb = (N + 255) / 256;
        k_final<<<nb, 256, 0, stream>>>(wnorm, batch, segsum, embs, N);
    }
}

// Round 8
// 1042.633 us; speedup vs baseline: 1.5379x; 1.5379x over previous
//
#include <hip/hip_runtime.h>

// QGrouping fused pipeline v4 (resubmit r8; r6/r7 never ran - GPU timeouts).
//   weights = x @ (Wq@Wk)^T + (Wq@bk+bq)   -- key[N,100] never materialized
//   e = exp(weights)  (no max-subtract: |w|<~8 bound, f32-safe; softmax shift-invariant)
//   k_main: thread t owns row t. x row streamed to REGISTERS (16 groups of 64B,
//   2-deep software pipeline) -- no LDS staging, no barriers until the final
//   reduce phase. Then e/val -> LDS, fused segment outer-product reduce.
// History: r3 (LDS-staged, barrier convoy): 433us, VALU 21.5%, hbm 8%,
//   VALU-work 93us confirmed. r5 (dbuf): REGRESSED 1106us, anomalous VALU 76%,
//   4M bank conflicts -- reverted. This version removes the convoy instead.

#define NSEG 128
#define KQ 8
#define VD 32
#define NOUT 40    // KQ + VD
#define INDIM 256
#define ROWS 256   // rows per block == block size
#define ESTR 12    // KQ+4: write banks 12*l mod 32, 2-way per 16 lanes (free)
#define VSTR 36    // VD+4: write banks 4*l mod 32, 2-way per 16 lanes (free)
#define SMEMF (ROWS * (ESTR + VSTR))   // 12288 floats = 48KB

// ---------------- setup: combined weights + zero embs/segsum ----------------
__global__ __launch_bounds__(256) void k_setup(
    const float* __restrict__ Wk, const float* __restrict__ bk,
    const float* __restrict__ Wq, const float* __restrict__ bq,
    const float* __restrict__ Wv, const float* __restrict__ bv,
    float* __restrict__ WO, float* __restrict__ bo,
    float* __restrict__ segsum, float* __restrict__ embs) {
    int b = blockIdx.x;
    int c = threadIdx.x;
    if (b < NOUT) {
        if (b < KQ) {
            float a = 0.f;
            for (int j = 0; j < 100; ++j) a = fmaf(Wq[b * 100 + j], Wk[j * INDIM + c], a);
            WO[b * INDIM + c] = a;
            if (c == 0) {
                float s = bq[b];
                for (int j = 0; j < 100; ++j) s = fmaf(Wq[b * 100 + j], bk[j], s);
                bo[b] = s;
            }
        } else {
            int v = b - KQ;
            WO[b * INDIM + c] = Wv[v * INDIM + c];
            if (c == 0) bo[b] = bv[v];
        }
    } else {
        int i = (b - NOUT) * 256 + c;
        if (i < NSEG * KQ * VD) {
            embs[i] = 0.f;
        } else {
            int j = i - NSEG * KQ * VD;
            if (j < NSEG * KQ) segsum[j] = 0.f;
        }
    }
}

// 16-column FMA block: buf = 4 float4 of this row's x, cc = column base.
// W addresses are wave-uniform (base + imm) -> s_load_dwordx4, proven in r3.
__device__ __forceinline__ void fma16(const float4* buf, const float* __restrict__ WO,
                                      int cc, float* acc) {
#pragma unroll
    for (int c4 = 0; c4 < 16; c4 += 4) {
        float4 xv = buf[c4 >> 2];
        const float* wp = &WO[cc + c4];
#pragma unroll
        for (int o = 0; o < NOUT; ++o) {
            const float* w = wp + o * INDIM;
            acc[o] = fmaf(xv.x, w[0],
                     fmaf(xv.y, w[1],
                     fmaf(xv.z, w[2],
                     fmaf(xv.w, w[3], acc[o]))));
        }
    }
}

// ---------------- main: reg-streamed GEMV + exp + fused seg-reduction ----------------
__global__ __launch_bounds__(ROWS, 3) void k_main(
    const float* __restrict__ x, const int* __restrict__ batch,
    const float* __restrict__ WO, const float* __restrict__ bo,
    float* __restrict__ eout,          // d_out norm_w region: holds e for now
    float* __restrict__ segsum, float* __restrict__ embs, int N) {
    __shared__ float smem[SMEMF];      // es | vs (reduce phase only)
    __shared__ int sg[ROWS];
    const int tid = threadIdx.x;
    const int row0 = blockIdx.x * ROWS;
    const int row = row0 + tid;
    const bool valid = row < N;

    sg[tid] = valid ? batch[row] : batch[N - 1];

    // clamp tail threads to a valid row; their results are masked to zero below
    const float* xr = x + (size_t)(valid ? row : (N - 1)) * INDIM;

    float acc[NOUT];
#pragma unroll
    for (int o = 0; o < NOUT; ++o) acc[o] = bo[o];   // uniform -> s_load

    // 2-deep pipelined row stream: 16 groups x 64B (4 x b128 per group).
    // Each lane consumes its full 64B line across the 4 loads -> no over-fetch.
    float4 bA[4], bB[4];
#pragma unroll
    for (int j = 0; j < 4; ++j) bA[j] = *(const float4*)&xr[j * 4];

    for (int g = 0; g < 16; g += 2) {          // g uniform -> scalar loop control
#pragma unroll
        for (int j = 0; j < 4; ++j) bB[j] = *(const float4*)&xr[(g + 1) * 16 + j * 4];
        fma16(bA, WO, g * 16, acc);            // ~640 FMA cover bB's latency
        if (g + 2 < 16) {
#pragma unroll
            for (int j = 0; j < 4; ++j) bA[j] = *(const float4*)&xr[(g + 2) * 16 + j * 4];
        }
        fma16(bB, WO, (g + 1) * 16, acc);      // ~640 FMA cover bA's latency
    }

    float e[KQ];
#pragma unroll
    for (int k = 0; k < KQ; ++k) e[k] = valid ? expf(acc[k]) : 0.f;

    if (valid) {   // stash unnormalized e; k_final normalizes in place
        *(float4*)&eout[(size_t)row * KQ]     = make_float4(e[0], e[1], e[2], e[3]);
        *(float4*)&eout[(size_t)row * KQ + 4] = make_float4(e[4], e[5], e[6], e[7]);
    }

    float* es = smem;                  // [ROWS][ESTR]
    float* vs = smem + ROWS * ESTR;    // [ROWS][VSTR]
    *(float4*)&es[tid * ESTR]     = make_float4(e[0], e[1], e[2], e[3]);
    *(float4*)&es[tid * ESTR + 4] = make_float4(e[4], e[5], e[6], e[7]);
#pragma unroll
    for (int i = 0; i < VD; i += 4) {
        float4 v = valid ? make_float4(acc[KQ + i], acc[KQ + i + 1],
                                       acc[KQ + i + 2], acc[KQ + i + 3])
                         : make_float4(0.f, 0.f, 0.f, 0.f);
        *(float4*)&vs[tid * VSTR + i] = v;
    }
    __syncthreads();   // the ONLY barrier in this kernel

    // thread owns one (k,vcol); serial over the block's 256 sorted rows.
    // es read: 2-address broadcast/wave. vs read: 32 distinct banks + bcast pair.
    const int kk = tid >> 5;       // 0..7
    const int vcol = tid & 31;
    float a0 = 0.f, s0 = 0.f;
    int cur = sg[0];
    for (int r = 0; r < ROWS; ++r) {
        int s = sg[r];                       // block-uniform (sorted segments)
        if (s != cur) {                      // rare (~1-2 flushes per block)
            atomicAdd(&embs[cur * (KQ * VD) + tid], a0);
            if (vcol == 0) atomicAdd(&segsum[cur * KQ + kk], s0);
            a0 = 0.f; s0 = 0.f; cur = s;
        }
        float ev = es[r * ESTR + kk];
        float vv = vs[r * VSTR + vcol];
        a0 = fmaf(ev, vv, a0);
        s0 += ev;
    }
    atomicAdd(&embs[cur * (KQ * VD) + tid], a0);
    if (vcol == 0) atomicAdd(&segsum[cur * KQ + kk], s0);
}

// ---------------- final: normalize embs and norm_w ----------------
__global__ __launch_bounds__(256) void k_final(
    float* __restrict__ wnorm, const int* __restrict__ batch,
    const float* __restrict__ segsum, float* __restrict__ embs, int N) {
    int gid = blockIdx.x * 256 + threadIdx.x;
    if (gid < NSEG * KQ * VD) {
        embs[gid] = embs[gid] / segsum[gid >> 5];   // (b*8+k) = gid>>5
    }
    if (gid < N) {
        int s = batch[gid];
        float4 e0 = *(float4*)&wnorm[(size_t)gid * KQ];
        float4 e1 = *(float4*)&wnorm[(size_t)gid * KQ + 4];
        const float* ss = &segsum[s * KQ];
        e0.x /= ss[0]; e0.y /= ss[1]; e0.z /= ss[2]; e0.w /= ss[3];
        e1.x /= ss[4]; e1.y /= ss[5]; e1.z /= ss[6]; e1.w /= ss[7];
        *(float4*)&wnorm[(size_t)gid * KQ]     = e0;
        *(float4*)&wnorm[(size_t)gid * KQ + 4] = e1;
    }
}

extern "C" void kernel_launch(void* const* d_in, const int* in_sizes, int n_in,
                              void* d_out, int out_size, void* d_ws, size_t ws_size,
                              hipStream_t stream) {
    const float* x   = (const float*)d_in[0];
    const int* batch = (const int*)d_in[1];
    const float* Wk  = (const float*)d_in[2];
    const float* bk  = (const float*)d_in[3];
    const float* Wq  = (const float*)d_in[4];
    const float* bq  = (const float*)d_in[5];
    const float* Wv  = (const float*)d_in[6];
    const float* bv  = (const float*)d_in[7];
    const int N = in_sizes[1];

    float* ws_f = (float*)d_ws;
    float* WO = ws_f;                                  // 40*256 floats
    float* bo = ws_f + NOUT * INDIM;                   // 40
    float* segsum = ws_f + NOUT * INDIM + NOUT + 8;    // 1024 floats, 16B-aligned

    float* embs  = (float*)d_out;                      // [128*8*32]
    float* wnorm = (float*)d_out + NSEG * KQ * VD;     // [N*8]: e -> norm_w in place

    {
        int nb = NOUT + (NSEG * KQ * VD + NSEG * KQ + 255) / 256;   // 40 + 132
        k_setup<<<nb, 256, 0, stream>>>(Wk, bk, Wq, bq, Wv, bv, WO, bo, segsum, embs);
    }
    {
        int nb = (N + ROWS - 1) / ROWS;
        k_main<<<nb, ROWS, 0, stream>>>(x, batch, WO, bo, wnorm, segsum, embs, N);
    }
    {
        int nb = (N + 255) / 256;
        k_final<<<nb, 256, 0, stream>>>(wnorm, batch, segsum, embs, N);
    }
}